// Round 1
// baseline (2734.923 us; speedup 1.0000x reference)
//
#include <hip/hip_runtime.h>
#include <math.h>

#define L 8
#define H 1024
#define NH 16
#define KVH 4
#define HD 64
#define INTER 2816
#define VOCAB 32000
#define CTX 2048
#define EPS 1e-5f

__device__ inline float wave_reduce_sum(float v) {
    #pragma unroll
    for (int off = 32; off > 0; off >>= 1)
        v += __shfl_xor(v, off, 64);
    return v;
}

// h = embed[input_ids[0]]
__global__ void embed_kernel(const float* __restrict__ embed, const int* __restrict__ ids,
                             float* __restrict__ h) {
    int t = threadIdx.x;                       // 256 threads, 4 floats each
    const float4* e4 = (const float4*)(embed + (size_t)ids[0] * H);
    ((float4*)h)[t] = e4[t];
}

// x = h * rsqrt(mean(h^2)+eps) * w      (single block, 256 threads, H=1024)
__global__ void rmsnorm_kernel(const float* __restrict__ h, const float* __restrict__ w,
                               float* __restrict__ x) {
    __shared__ float red[256];
    int t = threadIdx.x;
    float4 v = ((const float4*)h)[t];
    red[t] = v.x*v.x + v.y*v.y + v.z*v.z + v.w*v.w;
    __syncthreads();
    for (int off = 128; off > 0; off >>= 1) {
        if (t < off) red[t] += red[t + off];
        __syncthreads();
    }
    float rs = rsqrtf(red[0] / (float)H + EPS);
    float4 wv = ((const float4*)w)[t];
    float4 o;
    o.x = v.x * rs * wv.x; o.y = v.y * rs * wv.y;
    o.z = v.z * rs * wv.z; o.w = v.w * rs * wv.w;
    ((float4*)x)[t] = o;
}

// q/k/v matvec: 1536 rows total (1024 q, 256 k, 256 v), wave per row
__global__ void qkv_kernel(const float* __restrict__ qw, const float* __restrict__ kw,
                           const float* __restrict__ vw, const float* __restrict__ x,
                           float* __restrict__ q, float* __restrict__ k, float* __restrict__ v) {
    int wave = threadIdx.x >> 6, lane = threadIdx.x & 63;
    int row = blockIdx.x * 4 + wave;
    const float* W; float* out; int r;
    if (row < H)            { W = qw; out = q; r = row; }
    else if (row < H + 256) { W = kw; out = k; r = row - H; }
    else                    { W = vw; out = v; r = row - H - 256; }
    const float4* W4 = (const float4*)(W + (size_t)r * H);
    const float4* x4 = (const float4*)x;
    float acc = 0.f;
    #pragma unroll
    for (int i = lane; i < H/4; i += 64) {
        float4 a = W4[i], b = x4[i];
        acc += a.x*b.x + a.y*b.y + a.z*b.z + a.w*b.w;
    }
    acc = wave_reduce_sum(acc);
    if (lane == 0) out[r] = acc;
}

// in-place RoPE on q (16 heads) and k (4 heads); thread per (head, d<32) pair
__global__ void rope_kernel(float* __restrict__ q, float* __restrict__ k,
                            const float* __restrict__ cos_c, const float* __restrict__ sin_c,
                            const int* __restrict__ pos_p) {
    int t = blockIdx.x * blockDim.x + threadIdx.x;
    if (t >= (NH + KVH) * 32) return;
    int pos = pos_p[0];
    const float* cr = cos_c + (size_t)pos * HD;
    const float* sr = sin_c + (size_t)pos * HD;
    int head = t >> 5, d = t & 31;
    float* base = (head < NH) ? (q + head * HD) : (k + (head - NH) * HD);
    float a = base[d], b = base[d + 32];
    base[d]      = a * cr[d]      - b * sr[d];
    base[d + 32] = b * cr[d + 32] + a * sr[d + 32];
}

// one block per q-head; scores over 0..pos (pos uses new k/v), softmax, V-weighted sum
__global__ void attn_kernel(const float* __restrict__ q, const float* __restrict__ kx,
                            const float* __restrict__ vx, const float* __restrict__ kcache,
                            const float* __restrict__ vcache, const int* __restrict__ pos_p,
                            float* __restrict__ ao) {
    __shared__ float s[CTX];
    __shared__ float qs[HD];
    __shared__ float red[256];
    int h = blockIdx.x;
    int t = threadIdx.x;
    int lane = t & 63, wave = t >> 6;
    int kvh = h >> 2;                          // n_rep = NH/KVH = 4
    int pos = pos_p[0];
    int n = pos + 1;
    if (t < HD) qs[t] = q[h * HD + t];
    __syncthreads();
    const float scale = 0.125f;                // 1/sqrt(64)
    const float* K = kcache + (size_t)kvh * CTX * HD;
    for (int p = wave; p < n; p += 4) {
        const float* kr = (p == pos) ? (kx + kvh * HD) : (K + (size_t)p * HD);
        float v = qs[lane] * kr[lane];
        v = wave_reduce_sum(v);
        if (lane == 0) s[p] = v * scale;
    }
    __syncthreads();
    // block max
    float m = -INFINITY;
    for (int p = t; p < n; p += 256) m = fmaxf(m, s[p]);
    red[t] = m; __syncthreads();
    for (int off = 128; off > 0; off >>= 1) {
        if (t < off) red[t] = fmaxf(red[t], red[t + off]);
        __syncthreads();
    }
    m = red[0];
    __syncthreads();
    // exp + block sum
    float ssum = 0.f;
    for (int p = t; p < n; p += 256) { float e = expf(s[p] - m); s[p] = e; ssum += e; }
    red[t] = ssum; __syncthreads();
    for (int off = 128; off > 0; off >>= 1) {
        if (t < off) red[t] += red[t + off];
        __syncthreads();
    }
    float inv = 1.f / red[0];
    // out[d] = inv * sum_p s[p] * V[p][d];  thread t -> (group g = t>>6, dim d = t&63)
    const float* V = vcache + (size_t)kvh * CTX * HD;
    int d = lane, g = wave;
    float acc = 0.f;
    for (int p = g; p < n; p += 4) {
        const float* vr = (p == pos) ? (vx + kvh * HD) : (V + (size_t)p * HD);
        acc += s[p] * vr[d];
    }
    __syncthreads();
    red[t] = acc; __syncthreads();
    if (t < HD)
        ao[h * HD + d] = (red[d] + red[64 + d] + red[128 + d] + red[192 + d]) * inv;
}

// generic matvec, wave per row, optional residual: y[r] = (res?res[r]:0) + W[r,:].x
__global__ void matvec_kernel(const float* __restrict__ W, const float* __restrict__ x,
                              const float* __restrict__ res, float* __restrict__ y,
                              int nrows, int ncols) {
    int wave = threadIdx.x >> 6, lane = threadIdx.x & 63;
    int row = blockIdx.x * (blockDim.x >> 6) + wave;
    if (row >= nrows) return;
    const float4* W4 = (const float4*)(W + (size_t)row * ncols);
    const float4* x4 = (const float4*)x;
    int n4 = ncols >> 2;
    float acc = 0.f;
    for (int i = lane; i < n4; i += 64) {
        float4 a = W4[i], b = x4[i];
        acc += a.x*b.x + a.y*b.y + a.z*b.z + a.w*b.w;
    }
    acc = wave_reduce_sum(acc);
    if (lane == 0) y[row] = (res ? res[row] : 0.f) + acc;
}

// t[i] = silu(gate_w[i,:].x) * (up_w[i,:].x)  — wave per row, both rows in one pass
__global__ void gateup_kernel(const float* __restrict__ gw, const float* __restrict__ uw,
                              const float* __restrict__ x, float* __restrict__ t_out) {
    int wave = threadIdx.x >> 6, lane = threadIdx.x & 63;
    int row = blockIdx.x * 4 + wave;
    if (row >= INTER) return;
    const float4* g4 = (const float4*)(gw + (size_t)row * H);
    const float4* u4 = (const float4*)(uw + (size_t)row * H);
    const float4* x4 = (const float4*)x;
    float ag = 0.f, au = 0.f;
    #pragma unroll
    for (int i = lane; i < H/4; i += 64) {
        float4 b = x4[i];
        float4 a = g4[i];
        ag += a.x*b.x + a.y*b.y + a.z*b.z + a.w*b.w;
        float4 c = u4[i];
        au += c.x*b.x + c.y*b.y + c.z*b.z + c.w*b.w;
    }
    ag = wave_reduce_sum(ag);
    au = wave_reduce_sum(au);
    if (lane == 0) {
        float sg = ag / (1.f + expf(-ag));     // silu
        t_out[row] = sg * au;
    }
}

// single-block argmax over VOCAB logits; out[0]=(float)idx, out[1]=max
__global__ void argmax_kernel(const float* __restrict__ logits, float* __restrict__ out) {
    __shared__ float vmax[256];
    __shared__ int   vidx[256];
    int t = threadIdx.x;
    float m = -INFINITY; int mi = 0;
    for (int i = t; i < VOCAB; i += 256) {
        float v = logits[i];
        if (v > m) { m = v; mi = i; }          // strict > keeps first max in-stride
    }
    vmax[t] = m; vidx[t] = mi; __syncthreads();
    for (int off = 128; off > 0; off >>= 1) {
        if (t < off) {
            if (vmax[t + off] > vmax[t] ||
                (vmax[t + off] == vmax[t] && vidx[t + off] < vidx[t])) {
                vmax[t] = vmax[t + off]; vidx[t] = vidx[t + off];
            }
        }
        __syncthreads();
    }
    if (t == 0) { out[0] = (float)vidx[0]; out[1] = vmax[0]; }
}

extern "C" void kernel_launch(void* const* d_in, const int* in_sizes, int n_in,
                              void* d_out, int out_size, void* d_ws, size_t ws_size,
                              hipStream_t stream) {
    const float* embed   = (const float*)d_in[0];
    const float* q_w     = (const float*)d_in[1];
    const float* k_w     = (const float*)d_in[2];
    const float* v_w     = (const float*)d_in[3];
    const float* o_w     = (const float*)d_in[4];
    const float* gate_w  = (const float*)d_in[5];
    const float* up_w    = (const float*)d_in[6];
    const float* down_w  = (const float*)d_in[7];
    const float* ln1_w   = (const float*)d_in[8];
    const float* ln2_w   = (const float*)d_in[9];
    const float* norm_w  = (const float*)d_in[10];
    const float* lm_head = (const float*)d_in[11];
    const float* kv_cache= (const float*)d_in[12];
    const float* cos_c   = (const float*)d_in[13];
    const float* sin_c   = (const float*)d_in[14];
    // d_in[15] causal_mask, d_in[16] update_mask: semantics reproduced via position_ids
    const int* input_ids    = (const int*)d_in[17];
    const int* position_ids = (const int*)d_in[18];

    float* ws = (float*)d_ws;
    float* h      = ws;            // 1024
    float* h2     = ws + 1024;     // 1024
    float* x      = ws + 2048;     // 1024
    float* qb     = ws + 3072;     // 1024
    float* kb     = ws + 4096;     // 256
    float* vb     = ws + 4352;     // 256
    float* aob    = ws + 4608;     // 1024
    float* tb     = ws + 5632;     // 2816
    float* logits = ws + 8448;     // 32000

    embed_kernel<<<1, 256, 0, stream>>>(embed, input_ids, h);
    for (int l = 0; l < L; ++l) {
        rmsnorm_kernel<<<1, 256, 0, stream>>>(h, ln1_w + (size_t)l * H, x);
        qkv_kernel<<<(H + 2 * KVH * HD) / 4, 256, 0, stream>>>(
            q_w + (size_t)l * H * H, k_w + (size_t)l * KVH * HD * H,
            v_w + (size_t)l * KVH * HD * H, x, qb, kb, vb);
        rope_kernel<<<3, 256, 0, stream>>>(qb, kb, cos_c, sin_c, position_ids);
        attn_kernel<<<NH, 256, 0, stream>>>(
            qb, kb, vb,
            kv_cache + (size_t)l * KVH * CTX * HD,
            kv_cache + (size_t)(L + l) * KVH * CTX * HD,
            position_ids, aob);
        matvec_kernel<<<H / 4, 256, 0, stream>>>(
            o_w + (size_t)l * H * H, aob, h, h2, H, H);
        rmsnorm_kernel<<<1, 256, 0, stream>>>(h2, ln2_w + (size_t)l * H, x);
        gateup_kernel<<<INTER / 4, 256, 0, stream>>>(
            gate_w + (size_t)l * INTER * H, up_w + (size_t)l * INTER * H, x, tb);
        matvec_kernel<<<H / 4, 256, 0, stream>>>(
            down_w + (size_t)l * H * INTER, tb, h2, h, H, INTER);
    }
    rmsnorm_kernel<<<1, 256, 0, stream>>>(h, norm_w, x);
    matvec_kernel<<<VOCAB / 4, 256, 0, stream>>>(lm_head, x, nullptr, logits, VOCAB, H);
    argmax_kernel<<<1, 256, 0, stream>>>(logits, (float*)d_out);
}

// Round 2
// 831.979 us; speedup vs baseline: 3.2872x; 3.2872x over previous
//
#include <hip/hip_runtime.h>
#include <math.h>

#define L 8
#define H 1024
#define NH 16
#define KVH 4
#define HD 64
#define INTER 2816
#define VOCAB 32000
#define CTX 2048
#define EPS 1e-5f
#define NCHUNK 32          // CTX / 64
#define PART_STRIDE 68     // m, l, o[64], pad

__device__ inline float wave_reduce_sum(float v) {
    #pragma unroll
    for (int off = 32; off > 0; off >>= 1)
        v += __shfl_xor(v, off, 64);
    return v;
}

__device__ inline float wave_reduce_max(float v) {
    #pragma unroll
    for (int off = 32; off > 0; off >>= 1)
        v = fmaxf(v, __shfl_xor(v, off, 64));
    return v;
}

// h = embed[input_ids[0]]
__global__ void embed_kernel(const float* __restrict__ embed, const int* __restrict__ ids,
                             float* __restrict__ h) {
    int t = threadIdx.x;
    const float4* e4 = (const float4*)(embed + (size_t)ids[0] * H);
    ((float4*)h)[t] = e4[t];
}

// x = h * rsqrt(mean(h^2)+eps) * w      (single block, 256 threads, H=1024)
__global__ void rmsnorm_kernel(const float* __restrict__ h, const float* __restrict__ w,
                               float* __restrict__ x) {
    __shared__ float red[256];
    int t = threadIdx.x;
    float4 v = ((const float4*)h)[t];
    red[t] = v.x*v.x + v.y*v.y + v.z*v.z + v.w*v.w;
    __syncthreads();
    for (int off = 128; off > 0; off >>= 1) {
        if (t < off) red[t] += red[t + off];
        __syncthreads();
    }
    float rs = rsqrtf(red[0] / (float)H + EPS);
    float4 wv = ((const float4*)w)[t];
    float4 o;
    o.x = v.x * rs * wv.x; o.y = v.y * rs * wv.y;
    o.z = v.z * rs * wv.z; o.w = v.w * rs * wv.w;
    ((float4*)x)[t] = o;
}

// q/k/v matvec: 1536 rows total (1024 q, 256 k, 256 v), wave per row
__global__ void qkv_kernel(const float* __restrict__ qw, const float* __restrict__ kw,
                           const float* __restrict__ vw, const float* __restrict__ x,
                           float* __restrict__ q, float* __restrict__ k, float* __restrict__ v) {
    int wave = threadIdx.x >> 6, lane = threadIdx.x & 63;
    int row = blockIdx.x * 4 + wave;
    const float* W; float* out; int r;
    if (row < H)            { W = qw; out = q; r = row; }
    else if (row < H + 256) { W = kw; out = k; r = row - H; }
    else                    { W = vw; out = v; r = row - H - 256; }
    const float4* W4 = (const float4*)(W + (size_t)r * H);
    const float4* x4 = (const float4*)x;
    float acc = 0.f;
    #pragma unroll
    for (int i = lane; i < H/4; i += 64) {
        float4 a = W4[i], b = x4[i];
        acc += a.x*b.x + a.y*b.y + a.z*b.z + a.w*b.w;
    }
    acc = wave_reduce_sum(acc);
    if (lane == 0) out[r] = acc;
}

// in-place RoPE on q (16 heads) and k (4 heads); thread per (head, d<32) pair
__global__ void rope_kernel(float* __restrict__ q, float* __restrict__ k,
                            const float* __restrict__ cos_c, const float* __restrict__ sin_c,
                            const int* __restrict__ pos_p) {
    int t = blockIdx.x * blockDim.x + threadIdx.x;
    if (t >= (NH + KVH) * 32) return;
    int pos = pos_p[0];
    const float* cr = cos_c + (size_t)pos * HD;
    const float* sr = sin_c + (size_t)pos * HD;
    int head = t >> 5, d = t & 31;
    float* base = (head < NH) ? (q + head * HD) : (k + (head - NH) * HD);
    float a = base[d], b = base[d + 32];
    base[d]      = a * cr[d]      - b * sr[d];
    base[d + 32] = b * cr[d + 32] + a * sr[d + 32];
}

// ---- flash-decode split attention ----
// grid (NH, NCHUNK); each block handles 64 positions for one q-head.
// Writes per-chunk (m, l, o[64]) to part[(h*NCHUNK+c)*PART_STRIDE].
__global__ void attn_split_kernel(const float* __restrict__ q, const float* __restrict__ kx,
                                  const float* __restrict__ vx, const float* __restrict__ kcache,
                                  const float* __restrict__ vcache, const int* __restrict__ pos_p,
                                  float* __restrict__ part) {
    int h = blockIdx.x, c = blockIdx.y;
    int pos = pos_p[0];
    int p0 = c * 64;
    if (p0 > pos) return;                      // fully-masked chunk
    int t = threadIdx.x;
    __shared__ float Kt[64 * 65];              // transposed [d][p], stride 65 (conflict-free col reads)
    __shared__ float Vt[64 * 64];              // [p][d]
    __shared__ float qs[64];
    __shared__ float e_s[64];
    __shared__ float red[256];
    int kvh = h >> 2;                          // n_rep = 4
    const float* K = kcache + (size_t)kvh * CTX * HD;
    const float* V = vcache + (size_t)kvh * CTX * HD;
    if (t < 64) qs[t] = q[h * HD + t];
    // cooperative tile load: 1024 float4 per tile, 4 per thread, coalesced
    #pragma unroll
    for (int j = t; j < 1024; j += 256) {
        int p = j >> 4, dq = j & 15;
        int pg = p0 + p;
        float4 kv4, vv4;
        if (pg > pos) {
            kv4 = make_float4(0.f, 0.f, 0.f, 0.f); vv4 = kv4;
        } else if (pg == pos) {
            kv4 = *(const float4*)(kx + kvh * HD + dq * 4);
            vv4 = *(const float4*)(vx + kvh * HD + dq * 4);
        } else {
            kv4 = *(const float4*)(K + (size_t)pg * HD + dq * 4);
            vv4 = *(const float4*)(V + (size_t)pg * HD + dq * 4);
        }
        Kt[(4 * dq + 0) * 65 + p] = kv4.x;     // 2-way bank aliasing only (free)
        Kt[(4 * dq + 1) * 65 + p] = kv4.y;
        Kt[(4 * dq + 2) * 65 + p] = kv4.z;
        Kt[(4 * dq + 3) * 65 + p] = kv4.w;
        *(float4*)(Vt + p * 64 + dq * 4) = vv4;
    }
    __syncthreads();
    // wave 0: scores + chunk-local softmax stats
    if (t < 64) {
        int pg = p0 + t;
        float acc = 0.f;
        #pragma unroll 8
        for (int i = 0; i < 64; ++i)
            acc += qs[i] * Kt[i * 65 + t];     // qs broadcast; Kt conflict-free
        float s = (pg > pos) ? -INFINITY : acc * 0.125f;
        float m = wave_reduce_max(s);
        float e = (pg > pos) ? 0.f : expf(s - m);
        float lsum = wave_reduce_sum(e);
        e_s[t] = e;
        if (t == 0) {
            float* pb = part + (size_t)(h * NCHUNK + c) * PART_STRIDE;
            pb[0] = m; pb[1] = lsum;
        }
    }
    __syncthreads();
    // all 256 threads: partial output o_c[d] = sum_p e[p] * V[p][d]
    int g = t >> 6, d = t & 63;
    float acc = 0.f;
    #pragma unroll
    for (int pp = 0; pp < 16; ++pp) {
        int p = g * 16 + pp;
        acc += e_s[p] * Vt[p * 64 + d];        // e_s broadcast; Vt 2-way (free)
    }
    red[t] = acc;
    __syncthreads();
    if (t < 64) {
        float o = red[t] + red[64 + t] + red[128 + t] + red[192 + t];
        part[(size_t)(h * NCHUNK + c) * PART_STRIDE + 2 + t] = o;
    }
}

// combine partials: grid NH, 64 threads
__global__ void attn_combine_kernel(const float* __restrict__ part, const int* __restrict__ pos_p,
                                    float* __restrict__ ao) {
    int h = blockIdx.x, t = threadIdx.x;
    int pos = pos_p[0];
    int nc = (pos + 64) >> 6;                  // ceil((pos+1)/64)
    float M = -INFINITY;
    for (int c = 0; c < nc; ++c)
        M = fmaxf(M, part[(size_t)(h * NCHUNK + c) * PART_STRIDE]);
    float Lsum = 0.f, acc = 0.f;
    for (int c = 0; c < nc; ++c) {
        const float* pb = part + (size_t)(h * NCHUNK + c) * PART_STRIDE;
        float w = expf(pb[0] - M);
        Lsum += w * pb[1];
        acc  += w * pb[2 + t];
    }
    ao[h * HD + t] = acc / Lsum;
}

// generic matvec, wave per row, optional residual: y[r] = (res?res[r]:0) + W[r,:].x
__global__ void matvec_kernel(const float* __restrict__ W, const float* __restrict__ x,
                              const float* __restrict__ res, float* __restrict__ y,
                              int nrows, int ncols) {
    int wave = threadIdx.x >> 6, lane = threadIdx.x & 63;
    int row = blockIdx.x * (blockDim.x >> 6) + wave;
    if (row >= nrows) return;
    const float4* W4 = (const float4*)(W + (size_t)row * ncols);
    const float4* x4 = (const float4*)x;
    int n4 = ncols >> 2;
    float acc = 0.f;
    for (int i = lane; i < n4; i += 64) {
        float4 a = W4[i], b = x4[i];
        acc += a.x*b.x + a.y*b.y + a.z*b.z + a.w*b.w;
    }
    acc = wave_reduce_sum(acc);
    if (lane == 0) y[row] = (res ? res[row] : 0.f) + acc;
}

// t[i] = silu(gate_w[i,:].x) * (up_w[i,:].x)  — wave per row, both rows in one pass
__global__ void gateup_kernel(const float* __restrict__ gw, const float* __restrict__ uw,
                              const float* __restrict__ x, float* __restrict__ t_out) {
    int wave = threadIdx.x >> 6, lane = threadIdx.x & 63;
    int row = blockIdx.x * 4 + wave;
    if (row >= INTER) return;
    const float4* g4 = (const float4*)(gw + (size_t)row * H);
    const float4* u4 = (const float4*)(uw + (size_t)row * H);
    const float4* x4 = (const float4*)x;
    float ag = 0.f, au = 0.f;
    #pragma unroll
    for (int i = lane; i < H/4; i += 64) {
        float4 b = x4[i];
        float4 a = g4[i];
        ag += a.x*b.x + a.y*b.y + a.z*b.z + a.w*b.w;
        float4 c = u4[i];
        au += c.x*b.x + c.y*b.y + c.z*b.z + c.w*b.w;
    }
    ag = wave_reduce_sum(ag);
    au = wave_reduce_sum(au);
    if (lane == 0) {
        float sg = ag / (1.f + expf(-ag));     // silu
        t_out[row] = sg * au;
    }
}

// single-block argmax over VOCAB logits; out[0]=(float)idx, out[1]=max
__global__ void argmax_kernel(const float* __restrict__ logits, float* __restrict__ out) {
    __shared__ float vmax[256];
    __shared__ int   vidx[256];
    int t = threadIdx.x;
    float m = -INFINITY; int mi = 0;
    for (int i = t; i < VOCAB; i += 256) {
        float v = logits[i];
        if (v > m) { m = v; mi = i; }
    }
    vmax[t] = m; vidx[t] = mi; __syncthreads();
    for (int off = 128; off > 0; off >>= 1) {
        if (t < off) {
            if (vmax[t + off] > vmax[t] ||
                (vmax[t + off] == vmax[t] && vidx[t + off] < vidx[t])) {
                vmax[t] = vmax[t + off]; vidx[t] = vidx[t + off];
            }
        }
        __syncthreads();
    }
    if (t == 0) { out[0] = (float)vidx[0]; out[1] = vmax[0]; }
}

extern "C" void kernel_launch(void* const* d_in, const int* in_sizes, int n_in,
                              void* d_out, int out_size, void* d_ws, size_t ws_size,
                              hipStream_t stream) {
    const float* embed   = (const float*)d_in[0];
    const float* q_w     = (const float*)d_in[1];
    const float* k_w     = (const float*)d_in[2];
    const float* v_w     = (const float*)d_in[3];
    const float* o_w     = (const float*)d_in[4];
    const float* gate_w  = (const float*)d_in[5];
    const float* up_w    = (const float*)d_in[6];
    const float* down_w  = (const float*)d_in[7];
    const float* ln1_w   = (const float*)d_in[8];
    const float* ln2_w   = (const float*)d_in[9];
    const float* norm_w  = (const float*)d_in[10];
    const float* lm_head = (const float*)d_in[11];
    const float* kv_cache= (const float*)d_in[12];
    const float* cos_c   = (const float*)d_in[13];
    const float* sin_c   = (const float*)d_in[14];
    const int* input_ids    = (const int*)d_in[17];
    const int* position_ids = (const int*)d_in[18];

    float* ws = (float*)d_ws;
    float* h      = ws;            // 1024
    float* h2     = ws + 1024;     // 1024
    float* x      = ws + 2048;     // 1024
    float* qb     = ws + 3072;     // 1024
    float* kb     = ws + 4096;     // 256
    float* vb     = ws + 4352;     // 256
    float* aob    = ws + 4608;     // 1024
    float* tb     = ws + 5632;     // 2816
    float* logits = ws + 8448;     // 32000
    float* part   = ws + 40448;    // NH*NCHUNK*PART_STRIDE = 34816

    embed_kernel<<<1, 256, 0, stream>>>(embed, input_ids, h);
    for (int l = 0; l < L; ++l) {
        rmsnorm_kernel<<<1, 256, 0, stream>>>(h, ln1_w + (size_t)l * H, x);
        qkv_kernel<<<(H + 2 * KVH * HD) / 4, 256, 0, stream>>>(
            q_w + (size_t)l * H * H, k_w + (size_t)l * KVH * HD * H,
            v_w + (size_t)l * KVH * HD * H, x, qb, kb, vb);
        rope_kernel<<<3, 256, 0, stream>>>(qb, kb, cos_c, sin_c, position_ids);
        attn_split_kernel<<<dim3(NH, NCHUNK), 256, 0, stream>>>(
            qb, kb, vb,
            kv_cache + (size_t)l * KVH * CTX * HD,
            kv_cache + (size_t)(L + l) * KVH * CTX * HD,
            position_ids, part);
        attn_combine_kernel<<<NH, 64, 0, stream>>>(part, position_ids, aob);
        matvec_kernel<<<H / 4, 256, 0, stream>>>(
            o_w + (size_t)l * H * H, aob, h, h2, H, H);
        rmsnorm_kernel<<<1, 256, 0, stream>>>(h2, ln2_w + (size_t)l * H, x);
        gateup_kernel<<<INTER / 4, 256, 0, stream>>>(
            gate_w + (size_t)l * INTER * H, up_w + (size_t)l * INTER * H, x, tb);
        matvec_kernel<<<H / 4, 256, 0, stream>>>(
            down_w + (size_t)l * H * INTER, tb, h2, h, H, INTER);
    }
    rmsnorm_kernel<<<1, 256, 0, stream>>>(h, norm_w, x);
    matvec_kernel<<<VOCAB / 4, 256, 0, stream>>>(lm_head, x, nullptr, logits, VOCAB, H);
    argmax_kernel<<<1, 256, 0, stream>>>(logits, (float*)d_out);
}